// Round 1
// baseline (118.840 us; speedup 1.0000x reference)
//
#include <hip/hip_runtime.h>

#define IMG_H 1024
#define IMG_W 1024

static __device__ __forceinline__ int iclamp(int v, int lo, int hi) {
    return v < lo ? lo : (v > hi ? hi : v);
}

__global__ __launch_bounds__(256) void ae_fused(
    const float* __restrict__ img,
    const float* __restrict__ w_conv,
    const float* __restrict__ b_conv,
    const float* __restrict__ W_b,
    const float* __restrict__ b_b,
    const float* __restrict__ W_d,
    const float* __restrict__ b_d,
    float* __restrict__ out)
{
    const int n = blockIdx.x * blockDim.x + threadIdx.x;   // tile col, 0..511
    const int m = blockIdx.y;                              // tile row, 0..511
    const int b = blockIdx.z;                              // batch, 0..7

    // ---- uniform weights (broadcast loads, L1-resident) ----
    float wc[2][4], wd[2][4], wb[2][2];
    #pragma unroll
    for (int c = 0; c < 2; ++c) {
        #pragma unroll
        for (int t = 0; t < 4; ++t) {
            wc[c][t] = w_conv[c * 4 + t];
            wd[c][t] = W_d[c * 4 + t];
        }
    }
    wb[0][0] = W_b[0]; wb[0][1] = W_b[1];
    wb[1][0] = W_b[2]; wb[1][1] = W_b[3];
    const float bc0 = b_conv[0], bc1 = b_conv[1];
    const float bb0 = b_b[0],   bb1 = b_b[1];
    const float bd  = b_d[0];

    // ---- load 6x6 input region: rows 2m-2..2m+3, cols 2n-2..2n+3 (clamped; ----
    // ---- clamped cells feed only invalid border patches, which are skipped) ----
    float reg[6][6];
    const float* imgb = img + (size_t)b * IMG_H * IMG_W;
    #pragma unroll
    for (int r = 0; r < 6; ++r) {
        const int gr = iclamp(2 * m - 2 + r, 0, IMG_H - 1);
        const float* rowp = imgb + (size_t)gr * IMG_W;
        #pragma unroll
        for (int cc = 0; cc < 3; ++cc) {
            const int gc = iclamp(2 * n - 2 + 2 * cc, 0, IMG_W - 2); // even → 8B aligned
            const float2 v = *(const float2*)(rowp + gc);
            reg[r][2 * cc]     = v.x;
            reg[r][2 * cc + 1] = v.y;
        }
    }

    // ---- covering-patch validity; count is identical for all 4 tile pixels ----
    const int vr0 = (m >= 1);    // rs = 2m-2
    const int vr1 = (m <= 510);  // rs = 2m   (needs 2m <= 1020)
    const int vc0 = (n >= 1);    // cs = 2n-2
    const int vc1 = (n <= 510);  // cs = 2n
    const float rcnt = 1.0f / (float)((vr0 + vr1) * (vc0 + vc1));

    float acc[2][2] = {{0.f, 0.f}, {0.f, 0.f}};

    #pragma unroll
    for (int a = 0; a < 2; ++a) {           // a=0: rs=2m-2 (quad row i=1); a=1: rs=2m (i=0)
        if (!(a ? vr1 : vr0)) continue;
        const int br = 2 * a;               // region base row of this patch
        const int iq = 1 - a;
        #pragma unroll
        for (int e = 0; e < 2; ++e) {       // e=0: cs=2n-2 (quad col j=1); e=1: cs=2n (j=0)
            if (!(e ? vc1 : vc0)) continue;
            const int bc = 2 * e;
            const int jq = 1 - e;
            const int tm = iq * 2 + jq;     // unpool one-hot position for this quadrant

            // conv (2x2 stride-2, 2 ch) + ReLU over the 4x4 patch
            float v0[4], v1[4];
            #pragma unroll
            for (int j = 0; j < 2; ++j) {
                #pragma unroll
                for (int k = 0; k < 2; ++k) {
                    const float p00 = reg[br + 2 * j][bc + 2 * k];
                    const float p01 = reg[br + 2 * j][bc + 2 * k + 1];
                    const float p10 = reg[br + 2 * j + 1][bc + 2 * k];
                    const float p11 = reg[br + 2 * j + 1][bc + 2 * k + 1];
                    float s0 = p00 * wc[0][0] + p01 * wc[0][1] + p10 * wc[0][2] + p11 * wc[0][3] + bc0;
                    float s1 = p00 * wc[1][0] + p01 * wc[1][1] + p10 * wc[1][2] + p11 * wc[1][3] + bc1;
                    v0[j * 2 + k] = fmaxf(s0, 0.0f);
                    v1[j * 2 + k] = fmaxf(s1, 0.0f);
                }
            }
            // max + first-occurrence argmax per channel (matches jnp.argmax tie rule)
            int i0 = 0, i1 = 0;
            float m0 = v0[0], m1 = v1[0];
            #pragma unroll
            for (int t = 1; t < 4; ++t) {
                if (v0[t] > m0) { m0 = v0[t]; i0 = t; }
                if (v1[t] > m1) { m1 = v1[t]; i1 = t; }
            }
            // bottleneck: z = relu(vals @ W_b.T + b_b)
            const float z0 = fmaxf(m0 * wb[0][0] + m1 * wb[0][1] + bb0, 0.0f);
            const float z1 = fmaxf(m0 * wb[1][0] + m1 * wb[1][1] + bb1, 0.0f);
            // unpool mask for this quadrant
            const float g0 = (i0 == tm) ? z0 : 0.0f;
            const float g1 = (i1 == tm) ? z1 : 0.0f;
            // decode 2x2 sub-block + sigmoid, accumulate
            #pragma unroll
            for (int p = 0; p < 2; ++p) {
                #pragma unroll
                for (int q = 0; q < 2; ++q) {
                    const float t2 = g0 * wd[0][p * 2 + q] + g1 * wd[1][p * 2 + q] + bd;
                    acc[p][q] += 1.0f / (1.0f + __expf(-t2));
                }
            }
        }
    }

    float* outb = out + (size_t)b * IMG_H * IMG_W;
    float2 o0 = make_float2(acc[0][0] * rcnt, acc[0][1] * rcnt);
    float2 o1 = make_float2(acc[1][0] * rcnt, acc[1][1] * rcnt);
    *(float2*)(outb + (size_t)(2 * m)     * IMG_W + 2 * n) = o0;
    *(float2*)(outb + (size_t)(2 * m + 1) * IMG_W + 2 * n) = o1;
}

extern "C" void kernel_launch(void* const* d_in, const int* in_sizes, int n_in,
                              void* d_out, int out_size, void* d_ws, size_t ws_size,
                              hipStream_t stream) {
    const float* img    = (const float*)d_in[0];
    const float* w_conv = (const float*)d_in[1];
    const float* b_conv = (const float*)d_in[2];
    const float* W_b    = (const float*)d_in[3];
    const float* b_b    = (const float*)d_in[4];
    const float* W_d    = (const float*)d_in[5];
    const float* b_d    = (const float*)d_in[6];
    float* out = (float*)d_out;

    dim3 block(256, 1, 1);
    dim3 grid(512 / 256, 512, 8);   // x: tile-col chunks, y: tile row, z: batch
    ae_fused<<<grid, block, 0, stream>>>(img, w_conv, b_conv, W_b, b_b, W_d, b_d, out);
}

// Round 2
// 106.959 us; speedup vs baseline: 1.1111x; 1.1111x over previous
//
#include <hip/hip_runtime.h>

#define IMG_H 1024
#define IMG_W 1024
#define TILES 16                 // 16x16 output tiles per block (= 32x32 pixels)
#define NPJ 17                   // patches per dim incl. halo
#define NPATCH (NPJ * NPJ)       // 289
#define PSTR 20                  // padded floats per patch in LDS (80 B, 16B-aligned, bank-spread)

__global__ __launch_bounds__(256) void ae_fused(
    const float* __restrict__ img,
    const float* __restrict__ w_conv,
    const float* __restrict__ b_conv,
    const float* __restrict__ W_b,
    const float* __restrict__ b_b,
    const float* __restrict__ W_d,
    const float* __restrict__ b_d,
    float* __restrict__ out)
{
    __shared__ __align__(16) float dec[NPATCH * PSTR];   // 23120 B

    const int t  = threadIdx.x;
    const int n0 = blockIdx.x * TILES;   // tile col base
    const int m0 = blockIdx.y * TILES;   // tile row base
    const int b  = blockIdx.z;

    // uniform weights (scalar-cached broadcast loads)
    float wc[2][4], wd[2][4], wb[2][2];
    #pragma unroll
    for (int c = 0; c < 2; ++c) {
        #pragma unroll
        for (int q = 0; q < 4; ++q) {
            wc[c][q] = w_conv[c * 4 + q];
            wd[c][q] = W_d[c * 4 + q];
        }
    }
    wb[0][0] = W_b[0]; wb[0][1] = W_b[1];
    wb[1][0] = W_b[2]; wb[1][1] = W_b[3];
    const float bc0 = b_conv[0], bc1 = b_conv[1];
    const float bb0 = b_b[0],   bb1 = b_b[1];
    const float bd  = b_d[0];

    const float* imgb = img + (size_t)b * IMG_H * IMG_W;

    // ---------------- stage 1: one thread per patch (j = m0-1+lpj, k = n0-1+lpk) ----------------
    #pragma unroll
    for (int it = 0; it < 2; ++it) {
        const int lp = t + it * 256;
        if (lp < NPATCH) {
            const int lpj = lp / NPJ;
            const int lpk = lp - lpj * NPJ;
            const int j = m0 - 1 + lpj;
            const int k = n0 - 1 + lpk;
            float* d = &dec[lp * PSTR];
            if (j >= 0 && j <= 510 && k >= 0 && k <= 510) {
                // 4x4 input patch at rows 2j.., cols 2k..  (8B-aligned float2 loads)
                float p[4][4];
                const float* base = imgb + (size_t)(2 * j) * IMG_W + 2 * k;
                #pragma unroll
                for (int r = 0; r < 4; ++r) {
                    const float2 va = *(const float2*)(base + (size_t)r * IMG_W);
                    const float2 vb = *(const float2*)(base + (size_t)r * IMG_W + 2);
                    p[r][0] = va.x; p[r][1] = va.y; p[r][2] = vb.x; p[r][3] = vb.y;
                }
                // conv 2x2 stride-2, 2 ch, + ReLU  (expression order identical to R1 = bit-exact)
                float v0[4], v1[4];
                #pragma unroll
                for (int jj = 0; jj < 2; ++jj) {
                    #pragma unroll
                    for (int kk = 0; kk < 2; ++kk) {
                        const float p00 = p[2 * jj][2 * kk];
                        const float p01 = p[2 * jj][2 * kk + 1];
                        const float p10 = p[2 * jj + 1][2 * kk];
                        const float p11 = p[2 * jj + 1][2 * kk + 1];
                        const float s0 = p00 * wc[0][0] + p01 * wc[0][1] + p10 * wc[0][2] + p11 * wc[0][3] + bc0;
                        const float s1 = p00 * wc[1][0] + p01 * wc[1][1] + p10 * wc[1][2] + p11 * wc[1][3] + bc1;
                        v0[jj * 2 + kk] = fmaxf(s0, 0.0f);
                        v1[jj * 2 + kk] = fmaxf(s1, 0.0f);
                    }
                }
                // first-occurrence argmax (jnp tie rule)
                int i0 = 0, i1 = 0;
                float mx0 = v0[0], mx1 = v1[0];
                #pragma unroll
                for (int q = 1; q < 4; ++q) {
                    if (v0[q] > mx0) { mx0 = v0[q]; i0 = q; }
                    if (v1[q] > mx1) { mx1 = v1[q]; i1 = q; }
                }
                // bottleneck
                const float z0 = fmaxf(mx0 * wb[0][0] + mx1 * wb[0][1] + bb0, 0.0f);
                const float z1 = fmaxf(mx0 * wb[1][0] + mx1 * wb[1][1] + bb1, 0.0f);

                // inactive quadrants decode to sigmoid(bd) exactly (0*w + 0*w + bd == bd)
                const float sc = 1.0f / (1.0f + __expf(-bd));
                const float4 cq = make_float4(sc, sc, sc, sc);
                #pragma unroll
                for (int qd = 0; qd < 4; ++qd) *(float4*)(d + qd * 4) = cq;

                // quadrant holding ch0 argmax
                {
                    const float g0 = z0;
                    const float g1 = (i1 == i0) ? z1 : 0.0f;
                    float4 q;
                    q.x = 1.0f / (1.0f + __expf(-(g0 * wd[0][0] + g1 * wd[1][0] + bd)));
                    q.y = 1.0f / (1.0f + __expf(-(g0 * wd[0][1] + g1 * wd[1][1] + bd)));
                    q.z = 1.0f / (1.0f + __expf(-(g0 * wd[0][2] + g1 * wd[1][2] + bd)));
                    q.w = 1.0f / (1.0f + __expf(-(g0 * wd[0][3] + g1 * wd[1][3] + bd)));
                    *(float4*)(d + i0 * 4) = q;
                }
                // quadrant holding ch1 argmax (overwrites with identical bits if i1==i0)
                {
                    const float g0 = (i0 == i1) ? z0 : 0.0f;
                    const float g1 = z1;
                    float4 q;
                    q.x = 1.0f / (1.0f + __expf(-(g0 * wd[0][0] + g1 * wd[1][0] + bd)));
                    q.y = 1.0f / (1.0f + __expf(-(g0 * wd[0][1] + g1 * wd[1][1] + bd)));
                    q.z = 1.0f / (1.0f + __expf(-(g0 * wd[0][2] + g1 * wd[1][2] + bd)));
                    q.w = 1.0f / (1.0f + __expf(-(g0 * wd[0][3] + g1 * wd[1][3] + bd)));
                    *(float4*)(d + i1 * 4) = q;
                }
            } else {
                const float4 zq = make_float4(0.0f, 0.0f, 0.0f, 0.0f);
                #pragma unroll
                for (int qd = 0; qd < 4; ++qd) *(float4*)(d + qd * 4) = zq;
            }
        }
    }
    __syncthreads();

    // ---------------- stage 2: gather 4 quadrants per output 2x2 tile ----------------
    const int ty = t >> 4, tx = t & 15;
    const int m = m0 + ty, n = n0 + tx;
    float a0 = 0.f, a1 = 0.f, a2 = 0.f, a3 = 0.f;
    #pragma unroll
    for (int a = 0; a < 2; ++a) {        // a=0: patch j=m-1 (quad row 1); a=1: j=m (quad row 0)
        #pragma unroll
        for (int e = 0; e < 2; ++e) {    // e=0: patch k=n-1 (quad col 1); e=1: k=n (quad col 0)
            const int lp = (ty + a) * NPJ + (tx + e);
            const int qd = (1 - a) * 2 + (1 - e);
            const float4 q = *(const float4*)(dec + lp * PSTR + qd * 4);
            a0 += q.x; a1 += q.y; a2 += q.z; a3 += q.w;
        }
    }
    const float rcnt = 1.0f / (float)(((m >= 1) + (m <= 510)) * ((n >= 1) + (n <= 510)));
    float* outb = out + (size_t)b * IMG_H * IMG_W;
    *(float2*)(outb + (size_t)(2 * m) * IMG_W + 2 * n)     = make_float2(a0 * rcnt, a1 * rcnt);
    *(float2*)(outb + (size_t)(2 * m + 1) * IMG_W + 2 * n) = make_float2(a2 * rcnt, a3 * rcnt);
}

extern "C" void kernel_launch(void* const* d_in, const int* in_sizes, int n_in,
                              void* d_out, int out_size, void* d_ws, size_t ws_size,
                              hipStream_t stream) {
    const float* img    = (const float*)d_in[0];
    const float* w_conv = (const float*)d_in[1];
    const float* b_conv = (const float*)d_in[2];
    const float* W_b    = (const float*)d_in[3];
    const float* b_b    = (const float*)d_in[4];
    const float* W_d    = (const float*)d_in[5];
    const float* b_d    = (const float*)d_in[6];
    float* out = (float*)d_out;

    dim3 block(256, 1, 1);
    dim3 grid(512 / TILES, 512 / TILES, 8);   // 32 x 32 x 8 blocks
    ae_fused<<<grid, block, 0, stream>>>(img, w_conv, b_conv, W_b, b_b, W_d, b_d, out);
}